// Round 1
// baseline (16070.508 us; speedup 1.0000x reference)
//
#include <hip/hip_runtime.h>

// Problem constants
#define Bz   4
#define Sz   2048
#define Hh   16
#define Dd   64
#define HID  1024
#define Mrows (Bz*Sz)          // 8192
#define OUT_ELEMS  8388608     // 4*2048*1024
// probs: 4*16*2048*2048 = 268435456

#define F4(p) (*(const float4*)(p))

// ---------------------------------------------------------------- GEMM QKV
// C = A @ W^T + bias, A:[M,1024], W:[1024,1024]; out layout [B,H,S,D]
constexpr int BM = 128, BN = 128, BKK = 16;

__global__ __launch_bounds__(256) void gemm_qkv_k(
    const float* __restrict__ A,
    const float* __restrict__ Wq, const float* __restrict__ Wk, const float* __restrict__ Wv,
    const float* __restrict__ bq, const float* __restrict__ bk, const float* __restrict__ bv,
    float* __restrict__ Qo, float* __restrict__ Ko, float* __restrict__ Vo)
{
    const int K = HID;
    const float* W; const float* bias; float* out;
    if (blockIdx.z == 0)      { W = Wq; bias = bq; out = Qo; }
    else if (blockIdx.z == 1) { W = Wk; bias = bk; out = Ko; }
    else                      { W = Wv; bias = bv; out = Vo; }

    __shared__ float As[BKK][BM + 4];
    __shared__ float Bs[BKK][BN + 4];
    const int tid = threadIdx.x;
    const int row0 = blockIdx.x * BM, col0 = blockIdx.y * BN;
    const int ty = tid >> 4, tx = tid & 15;
    const int lr = tid >> 2, lk = (tid & 3) * 4;
    float acc[8][8] = {};

    for (int k0 = 0; k0 < K; k0 += BKK) {
        float4 a0 = F4(&A[(size_t)(row0 + lr) * K + k0 + lk]);
        float4 a1 = F4(&A[(size_t)(row0 + lr + 64) * K + k0 + lk]);
        float4 w0 = F4(&W[(size_t)(col0 + lr) * K + k0 + lk]);
        float4 w1 = F4(&W[(size_t)(col0 + lr + 64) * K + k0 + lk]);
        __syncthreads();
        As[lk+0][lr] = a0.x; As[lk+1][lr] = a0.y; As[lk+2][lr] = a0.z; As[lk+3][lr] = a0.w;
        As[lk+0][lr+64] = a1.x; As[lk+1][lr+64] = a1.y; As[lk+2][lr+64] = a1.z; As[lk+3][lr+64] = a1.w;
        Bs[lk+0][lr] = w0.x; Bs[lk+1][lr] = w0.y; Bs[lk+2][lr] = w0.z; Bs[lk+3][lr] = w0.w;
        Bs[lk+0][lr+64] = w1.x; Bs[lk+1][lr+64] = w1.y; Bs[lk+2][lr+64] = w1.z; Bs[lk+3][lr+64] = w1.w;
        __syncthreads();
        #pragma unroll
        for (int kk = 0; kk < BKK; ++kk) {
            float4 av0 = F4(&As[kk][ty*8]);   float4 av1 = F4(&As[kk][ty*8+4]);
            float4 bv0 = F4(&Bs[kk][tx*8]);   float4 bv1 = F4(&Bs[kk][tx*8+4]);
            float a[8] = {av0.x,av0.y,av0.z,av0.w,av1.x,av1.y,av1.z,av1.w};
            float bb[8] = {bv0.x,bv0.y,bv0.z,bv0.w,bv1.x,bv1.y,bv1.z,bv1.w};
            #pragma unroll
            for (int ii = 0; ii < 8; ++ii)
                #pragma unroll
                for (int jj = 0; jj < 8; ++jj)
                    acc[ii][jj] += a[ii] * bb[jj];
        }
    }
    // epilogue: [B,H,S,D]
    const int j = col0 + tx * 8;
    const int hh = j >> 6, dh = j & 63;
    float4 bias0 = F4(&bias[j]); float4 bias1 = F4(&bias[j+4]);
    #pragma unroll
    for (int ii = 0; ii < 8; ++ii) {
        int i = row0 + ty * 8 + ii;
        int bi = i >> 11, si = i & 2047;
        float* o = out + ((size_t)(bi * Hh + hh) * Sz + si) * Dd + dh;
        float4 o0 = make_float4(acc[ii][0]+bias0.x, acc[ii][1]+bias0.y, acc[ii][2]+bias0.z, acc[ii][3]+bias0.w);
        float4 o1 = make_float4(acc[ii][4]+bias1.x, acc[ii][5]+bias1.y, acc[ii][6]+bias1.z, acc[ii][7]+bias1.w);
        *(float4*)&o[0] = o0; *(float4*)&o[4] = o1;
    }
}

// ---------------------------------------------------------------- out-proj GEMM
// H = CTX @ Wo^T + bo + X  (flat [M,1024])
__global__ __launch_bounds__(256) void gemm_out_k(
    const float* __restrict__ A, const float* __restrict__ W,
    const float* __restrict__ bias, const float* __restrict__ resid,
    float* __restrict__ out)
{
    const int K = HID;
    __shared__ float As[BKK][BM + 4];
    __shared__ float Bs[BKK][BN + 4];
    const int tid = threadIdx.x;
    const int row0 = blockIdx.x * BM, col0 = blockIdx.y * BN;
    const int ty = tid >> 4, tx = tid & 15;
    const int lr = tid >> 2, lk = (tid & 3) * 4;
    float acc[8][8] = {};

    for (int k0 = 0; k0 < K; k0 += BKK) {
        float4 a0 = F4(&A[(size_t)(row0 + lr) * K + k0 + lk]);
        float4 a1 = F4(&A[(size_t)(row0 + lr + 64) * K + k0 + lk]);
        float4 w0 = F4(&W[(size_t)(col0 + lr) * K + k0 + lk]);
        float4 w1 = F4(&W[(size_t)(col0 + lr + 64) * K + k0 + lk]);
        __syncthreads();
        As[lk+0][lr] = a0.x; As[lk+1][lr] = a0.y; As[lk+2][lr] = a0.z; As[lk+3][lr] = a0.w;
        As[lk+0][lr+64] = a1.x; As[lk+1][lr+64] = a1.y; As[lk+2][lr+64] = a1.z; As[lk+3][lr+64] = a1.w;
        Bs[lk+0][lr] = w0.x; Bs[lk+1][lr] = w0.y; Bs[lk+2][lr] = w0.z; Bs[lk+3][lr] = w0.w;
        Bs[lk+0][lr+64] = w1.x; Bs[lk+1][lr+64] = w1.y; Bs[lk+2][lr+64] = w1.z; Bs[lk+3][lr+64] = w1.w;
        __syncthreads();
        #pragma unroll
        for (int kk = 0; kk < BKK; ++kk) {
            float4 av0 = F4(&As[kk][ty*8]);   float4 av1 = F4(&As[kk][ty*8+4]);
            float4 bv0 = F4(&Bs[kk][tx*8]);   float4 bv1 = F4(&Bs[kk][tx*8+4]);
            float a[8] = {av0.x,av0.y,av0.z,av0.w,av1.x,av1.y,av1.z,av1.w};
            float bb[8] = {bv0.x,bv0.y,bv0.z,bv0.w,bv1.x,bv1.y,bv1.z,bv1.w};
            #pragma unroll
            for (int ii = 0; ii < 8; ++ii)
                #pragma unroll
                for (int jj = 0; jj < 8; ++jj)
                    acc[ii][jj] += a[ii] * bb[jj];
        }
    }
    const int j = col0 + tx * 8;
    float4 bias0 = F4(&bias[j]); float4 bias1 = F4(&bias[j+4]);
    #pragma unroll
    for (int ii = 0; ii < 8; ++ii) {
        int i = row0 + ty * 8 + ii;
        float4 r0 = F4(&resid[(size_t)i * HID + j]);
        float4 r1 = F4(&resid[(size_t)i * HID + j + 4]);
        float* o = out + (size_t)i * HID + j;
        float4 o0 = make_float4(acc[ii][0]+bias0.x+r0.x, acc[ii][1]+bias0.y+r0.y,
                                acc[ii][2]+bias0.z+r0.z, acc[ii][3]+bias0.w+r0.w);
        float4 o1 = make_float4(acc[ii][4]+bias1.x+r1.x, acc[ii][5]+bias1.y+r1.y,
                                acc[ii][6]+bias1.z+r1.z, acc[ii][7]+bias1.w+r1.w);
        *(float4*)&o[0] = o0; *(float4*)&o[4] = o1;
    }
}

// ---------------------------------------------------------------- fused attention
// Per block: one (b,h), 8 q-rows. Scores in registers (thread owns k = i*256+tid, i=0..7).
__global__ __launch_bounds__(256) void attn_k(
    const float* __restrict__ Q, const float* __restrict__ Kx, const float* __restrict__ V,
    const float* __restrict__ mask, float* __restrict__ probs, float* __restrict__ ctx)
{
    const int bh = blockIdx.y;
    const int b = bh >> 4, h = bh & 15;
    const int q0 = blockIdx.x * 8;
    const int tid = threadIdx.x;
    const int lane = tid & 63, wid = tid >> 6;

    const float* Qbh = Q + (size_t)bh * Sz * Dd;
    const float* Kbh = Kx + (size_t)bh * Sz * Dd;
    const float* Vbh = V + (size_t)bh * Sz * Dd;
    const float* maskb = mask + (size_t)b * Sz;

    __shared__ float q_s[8][64];
    __shared__ float p_s[8][64];
    __shared__ float v_s[64][68];
    __shared__ float redm[8][4];
    __shared__ float reds[8][4];
    __shared__ float cred[4][8][64];

    for (int t = tid; t < 512; t += 256)
        q_s[t >> 6][t & 63] = Qbh[(size_t)(q0 + (t >> 6)) * Dd + (t & 63)];
    __syncthreads();

    // ---- phase 1: scores[r][i], k = i*256 + tid
    float acc[8][8];
    #pragma unroll
    for (int r = 0; r < 8; ++r)
        #pragma unroll
        for (int i = 0; i < 8; ++i) acc[r][i] = 0.f;

    #pragma unroll
    for (int ip = 0; ip < 4; ++ip) {
        const float* kp0 = Kbh + ((size_t)(ip * 512) + tid) * Dd;
        const float* kp1 = kp0 + (size_t)256 * Dd;
        #pragma unroll
        for (int dq = 0; dq < 4; ++dq) {
            float4 k0q[4], k1q[4];
            #pragma unroll
            for (int c = 0; c < 4; ++c) {
                k0q[c] = F4(&kp0[dq*16 + c*4]);
                k1q[c] = F4(&kp1[dq*16 + c*4]);
            }
            #pragma unroll
            for (int c = 0; c < 4; ++c) {
                int d0 = dq*16 + c*4;
                #pragma unroll
                for (int r = 0; r < 8; ++r) {
                    float4 q4 = F4(&q_s[r][d0]);
                    acc[r][2*ip]   += q4.x*k0q[c].x + q4.y*k0q[c].y + q4.z*k0q[c].z + q4.w*k0q[c].w;
                    acc[r][2*ip+1] += q4.x*k1q[c].x + q4.y*k1q[c].y + q4.z*k1q[c].z + q4.w*k1q[c].w;
                }
            }
        }
    }

    // scale + additive mask
    #pragma unroll
    for (int i = 0; i < 8; ++i) {
        float am = (1.0f - maskb[i*256 + tid]) * -10000.0f;
        #pragma unroll
        for (int r = 0; r < 8; ++r) acc[r][i] = acc[r][i] * 0.125f + am;
    }

    // ---- softmax: row max
    float gmax[8];
    #pragma unroll
    for (int r = 0; r < 8; ++r) {
        float m = acc[r][0];
        #pragma unroll
        for (int i = 1; i < 8; ++i) m = fmaxf(m, acc[r][i]);
        #pragma unroll
        for (int off = 32; off > 0; off >>= 1) m = fmaxf(m, __shfl_xor(m, off));
        if (lane == 0) redm[r][wid] = m;
    }
    __syncthreads();
    #pragma unroll
    for (int r = 0; r < 8; ++r)
        gmax[r] = fmaxf(fmaxf(redm[r][0], redm[r][1]), fmaxf(redm[r][2], redm[r][3]));

    // exp + row sum
    #pragma unroll
    for (int r = 0; r < 8; ++r) {
        float s = 0.f;
        #pragma unroll
        for (int i = 0; i < 8; ++i) { acc[r][i] = __expf(acc[r][i] - gmax[r]); s += acc[r][i]; }
        #pragma unroll
        for (int off = 32; off > 0; off >>= 1) s += __shfl_xor(s, off);
        if (lane == 0) reds[r][wid] = s;
    }
    __syncthreads();
    #pragma unroll
    for (int r = 0; r < 8; ++r) {
        float inv = 1.0f / (reds[r][0] + reds[r][1] + reds[r][2] + reds[r][3]);
        #pragma unroll
        for (int i = 0; i < 8; ++i) acc[r][i] *= inv;
    }

    // write probs (coalesced b32)
    float* pb = probs + ((size_t)bh * Sz + q0) * Sz;
    #pragma unroll
    for (int r = 0; r < 8; ++r)
        #pragma unroll
        for (int i = 0; i < 8; ++i)
            pb[(size_t)r * Sz + i*256 + tid] = acc[r][i];

    // ---- phase 2: PV.  ctx[r][d], d = lane; waves split kk quarters, partial sums.
    float cacc[8];
    #pragma unroll
    for (int r = 0; r < 8; ++r) cacc[r] = 0.f;

    for (int kt = 0; kt < 32; ++kt) {
        __syncthreads();
        if (wid == (kt & 3)) {
            int i = kt >> 2;
            #pragma unroll
            for (int r = 0; r < 8; ++r) p_s[r][lane] = acc[r][i];
        }
        for (int t = tid; t < 1024; t += 256) {
            int kk = t >> 4, d4 = (t & 15) * 4;
            float4 vv = F4(&Vbh[(size_t)((kt << 6) + kk) * Dd + d4]);
            v_s[d4+0][kk] = vv.x; v_s[d4+1][kk] = vv.y; v_s[d4+2][kk] = vv.z; v_s[d4+3][kk] = vv.w;
        }
        __syncthreads();
        #pragma unroll
        for (int c = 0; c < 4; ++c) {
            int kk0 = wid * 16 + c * 4;
            float4 vv = F4(&v_s[lane][kk0]);
            #pragma unroll
            for (int r = 0; r < 8; ++r) {
                float4 p4 = F4(&p_s[r][kk0]);
                cacc[r] += vv.x*p4.x + vv.y*p4.y + vv.z*p4.z + vv.w*p4.w;
            }
        }
    }
    __syncthreads();
    #pragma unroll
    for (int r = 0; r < 8; ++r) cred[wid][r][lane] = cacc[r];
    __syncthreads();
    #pragma unroll
    for (int rr = 0; rr < 2; ++rr) {
        int r = wid * 2 + rr;
        float v = cred[0][r][lane] + cred[1][r][lane] + cred[2][r][lane] + cred[3][r][lane];
        ctx[((size_t)(b * Sz + q0 + r) * Hh + h) * Dd + lane] = v;
    }
}

// ---------------------------------------------------------------- layernorm
__global__ __launch_bounds__(256) void ln_k(
    const float* __restrict__ Hb, const float* __restrict__ g,
    const float* __restrict__ bta, float* __restrict__ out)
{
    const int row = blockIdx.x, tid = threadIdx.x;
    const int lane = tid & 63, wid = tid >> 6;
    const float* x = Hb + (size_t)row * HID;
    float4 xv = F4(&x[tid * 4]);
    float s = xv.x + xv.y + xv.z + xv.w;
    float q = xv.x*xv.x + xv.y*xv.y + xv.z*xv.z + xv.w*xv.w;
    #pragma unroll
    for (int off = 32; off > 0; off >>= 1) { s += __shfl_xor(s, off); q += __shfl_xor(q, off); }
    __shared__ float rs[4], rq[4];
    if (lane == 0) { rs[wid] = s; rq[wid] = q; }
    __syncthreads();
    float S = rs[0] + rs[1] + rs[2] + rs[3];
    float Q2 = rq[0] + rq[1] + rq[2] + rq[3];
    float mu = S * (1.0f / HID);
    float var = Q2 * (1.0f / HID) - mu * mu;
    float inv = rsqrtf(var + 1e-12f);
    float4 g4 = F4(&g[tid*4]); float4 b4 = F4(&bta[tid*4]);
    float4 o;
    o.x = (xv.x - mu) * inv * g4.x + b4.x;
    o.y = (xv.y - mu) * inv * g4.y + b4.y;
    o.z = (xv.z - mu) * inv * g4.z + b4.z;
    o.w = (xv.w - mu) * inv * b4.w * 0.0f + (xv.w - mu) * inv * g4.w + b4.w; // keep simple:
    o.w = (xv.w - mu) * inv * g4.w + b4.w;
    *(float4*)&out[(size_t)row * HID + tid*4] = o;
}

// ---------------------------------------------------------------- launch
extern "C" void kernel_launch(void* const* d_in, const int* in_sizes, int n_in,
                              void* d_out, int out_size, void* d_ws, size_t ws_size,
                              hipStream_t stream) {
    (void)in_sizes; (void)n_in; (void)out_size; (void)ws_size;
    const float* X   = (const float*)d_in[0];
    const float* msk = (const float*)d_in[1];
    const float* Wq  = (const float*)d_in[2];  const float* bq = (const float*)d_in[3];
    const float* Wk  = (const float*)d_in[4];  const float* bk = (const float*)d_in[5];
    const float* Wv  = (const float*)d_in[6];  const float* bv = (const float*)d_in[7];
    const float* Wo  = (const float*)d_in[8];  const float* bo = (const float*)d_in[9];
    const float* lg  = (const float*)d_in[10]; const float* lb = (const float*)d_in[11];

    float* out   = (float*)d_out;
    float* probs = out + (size_t)OUT_ELEMS;
    float* ws    = (float*)d_ws;
    float* Qb  = ws;
    float* Kb  = ws + (size_t)8388608;
    float* Vb  = ws + (size_t)16777216;
    float* CT  = ws + (size_t)25165824;
    float* Hb  = ws;  // reuse Q region (dead after attn)

    gemm_qkv_k<<<dim3(Mrows/BM, HID/BN, 3), 256, 0, stream>>>(X, Wq, Wk, Wv, bq, bk, bv, Qb, Kb, Vb);
    attn_k<<<dim3(Sz/8, Bz*Hh), 256, 0, stream>>>(Qb, Kb, Vb, msk, probs, CT);
    gemm_out_k<<<dim3(Mrows/BM, HID/BN), 256, 0, stream>>>(CT, Wo, bo, X, Hb);
    ln_k<<<dim3(Mrows), 256, 0, stream>>>(Hb, lg, lb, out);
}

// Round 2
// 2163.949 us; speedup vs baseline: 7.4265x; 7.4265x over previous
//
#include <hip/hip_runtime.h>

// Problem constants
#define Bz   4
#define Sz   2048
#define Hh   16
#define Dd   64
#define HID  1024
#define Mrows (Bz*Sz)          // 8192
#define OUT_ELEMS  8388608     // 4*2048*1024

#define F4(p) (*(const float4*)(p))

typedef __attribute__((ext_vector_type(8))) short bf16x8;
typedef __attribute__((ext_vector_type(4))) float f32x4;

__device__ __forceinline__ ushort f2bf(float f) {
    uint u = __float_as_uint(f);
    uint r = (u + 0x7fffu + ((u >> 16) & 1u)) >> 16;   // RNE
    return (ushort)r;
}
__device__ __forceinline__ uint pack2(float x, float y) {
    return (uint)f2bf(x) | ((uint)f2bf(y) << 16);
}

// ---------------------------------------------------------------- GEMM QKV (fp32 compute, bf16 out)
// C = A @ W^T + bias; Q,K out: bf16 [bh][s][d]; V out: bf16 transposed [bh][d][s]
constexpr int BM = 128, BN = 128, BKK = 16;

__global__ __launch_bounds__(256) void gemm_qkv_k(
    const float* __restrict__ A,
    const float* __restrict__ Wq, const float* __restrict__ Wk, const float* __restrict__ Wv,
    const float* __restrict__ bq, const float* __restrict__ bk, const float* __restrict__ bv,
    ushort* __restrict__ Qo, ushort* __restrict__ Ko, ushort* __restrict__ Vo)
{
    const int K = HID;
    const float* W; const float* bias;
    if (blockIdx.z == 0)      { W = Wq; bias = bq; }
    else if (blockIdx.z == 1) { W = Wk; bias = bk; }
    else                      { W = Wv; bias = bv; }

    __shared__ float As[BKK][BM + 4];
    __shared__ float Bs[BKK][BN + 4];
    const int tid = threadIdx.x;
    const int row0 = blockIdx.x * BM, col0 = blockIdx.y * BN;
    const int ty = tid >> 4, tx = tid & 15;
    const int lr = tid >> 2, lk = (tid & 3) * 4;
    float acc[8][8] = {};

    for (int k0 = 0; k0 < K; k0 += BKK) {
        float4 a0 = F4(&A[(size_t)(row0 + lr) * K + k0 + lk]);
        float4 a1 = F4(&A[(size_t)(row0 + lr + 64) * K + k0 + lk]);
        float4 w0 = F4(&W[(size_t)(col0 + lr) * K + k0 + lk]);
        float4 w1 = F4(&W[(size_t)(col0 + lr + 64) * K + k0 + lk]);
        __syncthreads();
        As[lk+0][lr] = a0.x; As[lk+1][lr] = a0.y; As[lk+2][lr] = a0.z; As[lk+3][lr] = a0.w;
        As[lk+0][lr+64] = a1.x; As[lk+1][lr+64] = a1.y; As[lk+2][lr+64] = a1.z; As[lk+3][lr+64] = a1.w;
        Bs[lk+0][lr] = w0.x; Bs[lk+1][lr] = w0.y; Bs[lk+2][lr] = w0.z; Bs[lk+3][lr] = w0.w;
        Bs[lk+0][lr+64] = w1.x; Bs[lk+1][lr+64] = w1.y; Bs[lk+2][lr+64] = w1.z; Bs[lk+3][lr+64] = w1.w;
        __syncthreads();
        #pragma unroll
        for (int kk = 0; kk < BKK; ++kk) {
            float4 av0 = F4(&As[kk][ty*8]);   float4 av1 = F4(&As[kk][ty*8+4]);
            float4 bv0 = F4(&Bs[kk][tx*8]);   float4 bv1 = F4(&Bs[kk][tx*8+4]);
            float a[8] = {av0.x,av0.y,av0.z,av0.w,av1.x,av1.y,av1.z,av1.w};
            float bb[8] = {bv0.x,bv0.y,bv0.z,bv0.w,bv1.x,bv1.y,bv1.z,bv1.w};
            #pragma unroll
            for (int ii = 0; ii < 8; ++ii)
                #pragma unroll
                for (int jj = 0; jj < 8; ++jj)
                    acc[ii][jj] += a[ii] * bb[jj];
        }
    }
    const int j = col0 + tx * 8;
    const int hh = j >> 6, dh = j & 63;
    float4 bias0 = F4(&bias[j]); float4 bias1 = F4(&bias[j+4]);

    if (blockIdx.z < 2) {
        ushort* ob = (blockIdx.z == 0) ? Qo : Ko;
        #pragma unroll
        for (int ii = 0; ii < 8; ++ii) {
            int i = row0 + ty * 8 + ii;
            int bi = i >> 11, si = i & 2047;
            ushort* o = ob + ((size_t)(bi * Hh + hh) * Sz + si) * Dd + dh;
            uint4 u;
            u.x = pack2(acc[ii][0]+bias0.x, acc[ii][1]+bias0.y);
            u.y = pack2(acc[ii][2]+bias0.z, acc[ii][3]+bias0.w);
            u.z = pack2(acc[ii][4]+bias1.x, acc[ii][5]+bias1.y);
            u.w = pack2(acc[ii][6]+bias1.z, acc[ii][7]+bias1.w);
            *(uint4*)o = u;
        }
    } else {
        int i0 = row0 + ty * 8;
        int bi = i0 >> 11, si0 = i0 & 2047;
        float bb[8] = {bias0.x,bias0.y,bias0.z,bias0.w,bias1.x,bias1.y,bias1.z,bias1.w};
        #pragma unroll
        for (int jj = 0; jj < 8; ++jj) {
            ushort* o = Vo + ((size_t)(bi * Hh + hh) * Dd + dh + jj) * Sz + si0;
            uint4 u;
            u.x = pack2(acc[0][jj]+bb[jj], acc[1][jj]+bb[jj]);
            u.y = pack2(acc[2][jj]+bb[jj], acc[3][jj]+bb[jj]);
            u.z = pack2(acc[4][jj]+bb[jj], acc[5][jj]+bb[jj]);
            u.w = pack2(acc[6][jj]+bb[jj], acc[7][jj]+bb[jj]);
            *(uint4*)o = u;
        }
    }
}

// ---------------------------------------------------------------- out-proj GEMM (unchanged fp32)
__global__ __launch_bounds__(256) void gemm_out_k(
    const float* __restrict__ A, const float* __restrict__ W,
    const float* __restrict__ bias, const float* __restrict__ resid,
    float* __restrict__ out)
{
    const int K = HID;
    __shared__ float As[BKK][BM + 4];
    __shared__ float Bs[BKK][BN + 4];
    const int tid = threadIdx.x;
    const int row0 = blockIdx.x * BM, col0 = blockIdx.y * BN;
    const int ty = tid >> 4, tx = tid & 15;
    const int lr = tid >> 2, lk = (tid & 3) * 4;
    float acc[8][8] = {};

    for (int k0 = 0; k0 < K; k0 += BKK) {
        float4 a0 = F4(&A[(size_t)(row0 + lr) * K + k0 + lk]);
        float4 a1 = F4(&A[(size_t)(row0 + lr + 64) * K + k0 + lk]);
        float4 w0 = F4(&W[(size_t)(col0 + lr) * K + k0 + lk]);
        float4 w1 = F4(&W[(size_t)(col0 + lr + 64) * K + k0 + lk]);
        __syncthreads();
        As[lk+0][lr] = a0.x; As[lk+1][lr] = a0.y; As[lk+2][lr] = a0.z; As[lk+3][lr] = a0.w;
        As[lk+0][lr+64] = a1.x; As[lk+1][lr+64] = a1.y; As[lk+2][lr+64] = a1.z; As[lk+3][lr+64] = a1.w;
        Bs[lk+0][lr] = w0.x; Bs[lk+1][lr] = w0.y; Bs[lk+2][lr] = w0.z; Bs[lk+3][lr] = w0.w;
        Bs[lk+0][lr+64] = w1.x; Bs[lk+1][lr+64] = w1.y; Bs[lk+2][lr+64] = w1.z; Bs[lk+3][lr+64] = w1.w;
        __syncthreads();
        #pragma unroll
        for (int kk = 0; kk < BKK; ++kk) {
            float4 av0 = F4(&As[kk][ty*8]);   float4 av1 = F4(&As[kk][ty*8+4]);
            float4 bv0 = F4(&Bs[kk][tx*8]);   float4 bv1 = F4(&Bs[kk][tx*8+4]);
            float a[8] = {av0.x,av0.y,av0.z,av0.w,av1.x,av1.y,av1.z,av1.w};
            float bb[8] = {bv0.x,bv0.y,bv0.z,bv0.w,bv1.x,bv1.y,bv1.z,bv1.w};
            #pragma unroll
            for (int ii = 0; ii < 8; ++ii)
                #pragma unroll
                for (int jj = 0; jj < 8; ++jj)
                    acc[ii][jj] += a[ii] * bb[jj];
        }
    }
    const int j = col0 + tx * 8;
    float4 bias0 = F4(&bias[j]); float4 bias1 = F4(&bias[j+4]);
    #pragma unroll
    for (int ii = 0; ii < 8; ++ii) {
        int i = row0 + ty * 8 + ii;
        float4 r0 = F4(&resid[(size_t)i * HID + j]);
        float4 r1 = F4(&resid[(size_t)i * HID + j + 4]);
        float* o = out + (size_t)i * HID + j;
        float4 o0 = make_float4(acc[ii][0]+bias0.x+r0.x, acc[ii][1]+bias0.y+r0.y,
                                acc[ii][2]+bias0.z+r0.z, acc[ii][3]+bias0.w+r0.w);
        float4 o1 = make_float4(acc[ii][4]+bias1.x+r1.x, acc[ii][5]+bias1.y+r1.y,
                                acc[ii][6]+bias1.z+r1.z, acc[ii][7]+bias1.w+r1.w);
        *(float4*)&o[0] = o0; *(float4*)&o[4] = o1;
    }
}

// ---------------------------------------------------------------- MFMA attention
// Block: one (b,h), 64 q-rows, 256 thr = 4 waves (wave w owns q rows w*16..+15).
// Two passes over k-tiles of 64: pass1 = online max/sum; pass2 = exact P,
// write fp32 probs, P->bf16 via swizzled LDS, PV MFMA.
// LDS swizzle: 16B granule gi ^= (row&7)  (G4 fix for 128B-row tiles).
__global__ __launch_bounds__(256, 4) void attn_k(
    const ushort* __restrict__ Qb, const ushort* __restrict__ Kb, const ushort* __restrict__ Vtb,
    const float* __restrict__ mask, float* __restrict__ probs, float* __restrict__ ctx)
{
    __shared__ ushort Qs[64*64];
    __shared__ ushort Ks[64*64];
    __shared__ ushort Vts[64*64];
    __shared__ ushort Pb[4*16*64];

    const int tid = threadIdx.x;
    const int lane = tid & 63, w = tid >> 6;
    const int bh = blockIdx.y, b = bh >> 4, h = bh & 15;
    const int q0 = blockIdx.x * 64;

    const ushort* Qg = Qb + ((size_t)bh * Sz + q0) * Dd;
    const ushort* Kg = Kb + (size_t)bh * Sz * Dd;
    const ushort* Vg = Vtb + (size_t)bh * Dd * Sz;
    const float*  mb = mask + (size_t)b * Sz;

    // stage Q once (swizzled)
    {
        int G = tid * 2, row = G >> 3, gi = G & 7;
        const uint4* src = (const uint4*)(Qg + row * 64 + gi * 8);
        uint4 v0 = src[0], v1 = src[1];
        *(uint4*)(Qs + row * 64 + ((gi       ^ (row & 7)) << 3)) = v0;
        *(uint4*)(Qs + row * 64 + (((gi + 1) ^ (row & 7)) << 3)) = v1;
    }

    const int rq = w * 16 + (lane & 15);   // A-frag q row (input mapping)
    const int g  = lane >> 4;              // k-slot group (input) / row group (output)
    const int c  = lane & 15;              // output col within 16-tile

    float m_[4], l_[4];
    #pragma unroll
    for (int j = 0; j < 4; ++j) { m_[j] = -1e30f; l_[j] = 0.f; }

    // ---------------- pass 1: online row max / sum
    for (int kt = 0; kt < 32; ++kt) {
        __syncthreads();
        {
            int G = tid * 2, row = G >> 3, gi = G & 7;
            const uint4* src = (const uint4*)(Kg + (size_t)(kt * 64 + row) * 64 + gi * 8);
            uint4 v0 = src[0], v1 = src[1];
            *(uint4*)(Ks + row * 64 + ((gi       ^ (row & 7)) << 3)) = v0;
            *(uint4*)(Ks + row * 64 + (((gi + 1) ^ (row & 7)) << 3)) = v1;
        }
        __syncthreads();

        f32x4 s[4] = {};
        #pragma unroll
        for (int kk = 0; kk < 2; ++kk) {
            bf16x8 a = *(const bf16x8*)(Qs + rq * 64 + ((((kk << 2) | g) ^ (rq & 7)) << 3));
            #pragma unroll
            for (int n = 0; n < 4; ++n) {
                int rk = n * 16 + c;
                bf16x8 bf = *(const bf16x8*)(Ks + rk * 64 + ((((kk << 2) | g) ^ (rk & 7)) << 3));
                s[n] = __builtin_amdgcn_mfma_f32_16x16x32_bf16(a, bf, s[n], 0, 0, 0);
            }
        }
        float am[4];
        #pragma unroll
        for (int n = 0; n < 4; ++n) am[n] = (1.0f - mb[kt * 64 + n * 16 + c]) * -10000.0f;
        #pragma unroll
        for (int j = 0; j < 4; ++j) {
            float x0 = s[0][j] * 0.125f + am[0];
            float x1 = s[1][j] * 0.125f + am[1];
            float x2 = s[2][j] * 0.125f + am[2];
            float x3 = s[3][j] * 0.125f + am[3];
            float mt = fmaxf(fmaxf(x0, x1), fmaxf(x2, x3));
            mt = fmaxf(mt, __shfl_xor(mt, 1));
            mt = fmaxf(mt, __shfl_xor(mt, 2));
            mt = fmaxf(mt, __shfl_xor(mt, 4));
            mt = fmaxf(mt, __shfl_xor(mt, 8));
            float mn = fmaxf(m_[j], mt);
            float ps = __expf(x0 - mn) + __expf(x1 - mn) + __expf(x2 - mn) + __expf(x3 - mn);
            ps += __shfl_xor(ps, 1); ps += __shfl_xor(ps, 2);
            ps += __shfl_xor(ps, 4); ps += __shfl_xor(ps, 8);
            l_[j] = l_[j] * __expf(m_[j] - mn) + ps;
            m_[j] = mn;
        }
    }
    float invl[4];
    #pragma unroll
    for (int j = 0; j < 4; ++j) invl[j] = 1.0f / l_[j];

    f32x4 o_[4] = {};
    float* pbase = probs + ((size_t)bh * Sz + (q0 + w * 16)) * Sz;
    ushort* Pw = Pb + w * 1024;

    // ---------------- pass 2: exact P, probs write, PV
    for (int kt = 0; kt < 32; ++kt) {
        __syncthreads();
        {
            int G = tid * 2, row = G >> 3, gi = G & 7;
            const uint4* src = (const uint4*)(Kg + (size_t)(kt * 64 + row) * 64 + gi * 8);
            uint4 v0 = src[0], v1 = src[1];
            *(uint4*)(Ks + row * 64 + ((gi       ^ (row & 7)) << 3)) = v0;
            *(uint4*)(Ks + row * 64 + (((gi + 1) ^ (row & 7)) << 3)) = v1;
            const uint4* sv = (const uint4*)(Vg + (size_t)row * Sz + kt * 64 + gi * 8);
            uint4 u0 = sv[0], u1 = sv[1];
            *(uint4*)(Vts + row * 64 + ((gi       ^ (row & 7)) << 3)) = u0;
            *(uint4*)(Vts + row * 64 + (((gi + 1) ^ (row & 7)) << 3)) = u1;
        }
        __syncthreads();

        f32x4 s[4] = {};
        #pragma unroll
        for (int kk = 0; kk < 2; ++kk) {
            bf16x8 a = *(const bf16x8*)(Qs + rq * 64 + ((((kk << 2) | g) ^ (rq & 7)) << 3));
            #pragma unroll
            for (int n = 0; n < 4; ++n) {
                int rk = n * 16 + c;
                bf16x8 bf = *(const bf16x8*)(Ks + rk * 64 + ((((kk << 2) | g) ^ (rk & 7)) << 3));
                s[n] = __builtin_amdgcn_mfma_f32_16x16x32_bf16(a, bf, s[n], 0, 0, 0);
            }
        }
        float am[4];
        #pragma unroll
        for (int n = 0; n < 4; ++n) am[n] = (1.0f - mb[kt * 64 + n * 16 + c]) * -10000.0f;

        #pragma unroll
        for (int j = 0; j < 4; ++j) {
            #pragma unroll
            for (int n = 0; n < 4; ++n) {
                float p = __expf(s[n][j] * 0.125f + am[n] - m_[j]) * invl[j];
                s[n][j] = p;
                pbase[(size_t)(g * 4 + j) * Sz + kt * 64 + n * 16 + c] = p;
            }
        }
        // transpose P -> bf16 swizzled LDS (per-wave region)
        #pragma unroll
        for (int j = 0; j < 4; ++j) {
            int row = g * 4 + j;
            #pragma unroll
            for (int n = 0; n < 4; ++n) {
                int col = n * 16 + c;
                Pw[row * 64 + (col ^ ((row & 7) << 3))] = f2bf(s[n][j]);
            }
        }
        // PV MFMA (same-wave ds write->read ordered via lgkmcnt)
        #pragma unroll
        for (int kk = 0; kk < 2; ++kk) {
            bf16x8 pa = *(const bf16x8*)(Pw + c * 64 + ((((kk << 2) | g) ^ (c & 7)) << 3));
            #pragma unroll
            for (int n = 0; n < 4; ++n) {
                int rv = n * 16 + c;
                bf16x8 vb = *(const bf16x8*)(Vts + rv * 64 + ((((kk << 2) | g) ^ (rv & 7)) << 3));
                o_[n] = __builtin_amdgcn_mfma_f32_16x16x32_bf16(pa, vb, o_[n], 0, 0, 0);
            }
        }
    }

    // ctx fp32 [b][s][HID]
    #pragma unroll
    for (int j = 0; j < 4; ++j) {
        int q = q0 + w * 16 + g * 4 + j;
        float* cw = ctx + ((size_t)b * Sz + q) * HID + h * Dd;
        #pragma unroll
        for (int n = 0; n < 4; ++n) cw[n * 16 + c] = o_[n][j];
    }
}

// ---------------------------------------------------------------- layernorm
__global__ __launch_bounds__(256) void ln_k(
    const float* __restrict__ Hb, const float* __restrict__ g,
    const float* __restrict__ bta, float* __restrict__ out)
{
    const int row = blockIdx.x, tid = threadIdx.x;
    const int lane = tid & 63, wid = tid >> 6;
    const float* x = Hb + (size_t)row * HID;
    float4 xv = F4(&x[tid * 4]);
    float s = xv.x + xv.y + xv.z + xv.w;
    float q = xv.x*xv.x + xv.y*xv.y + xv.z*xv.z + xv.w*xv.w;
    #pragma unroll
    for (int off = 32; off > 0; off >>= 1) { s += __shfl_xor(s, off); q += __shfl_xor(q, off); }
    __shared__ float rs[4], rq[4];
    if (lane == 0) { rs[wid] = s; rq[wid] = q; }
    __syncthreads();
    float S = rs[0] + rs[1] + rs[2] + rs[3];
    float Q2 = rq[0] + rq[1] + rq[2] + rq[3];
    float mu = S * (1.0f / HID);
    float var = Q2 * (1.0f / HID) - mu * mu;
    float inv = rsqrtf(var + 1e-12f);
    float4 g4 = F4(&g[tid*4]); float4 b4 = F4(&bta[tid*4]);
    float4 o;
    o.x = (xv.x - mu) * inv * g4.x + b4.x;
    o.y = (xv.y - mu) * inv * g4.y + b4.y;
    o.z = (xv.z - mu) * inv * g4.z + b4.z;
    o.w = (xv.w - mu) * inv * g4.w + b4.w;
    *(float4*)&out[(size_t)row * HID + tid*4] = o;
}

// ---------------------------------------------------------------- launch
extern "C" void kernel_launch(void* const* d_in, const int* in_sizes, int n_in,
                              void* d_out, int out_size, void* d_ws, size_t ws_size,
                              hipStream_t stream) {
    (void)in_sizes; (void)n_in; (void)out_size; (void)ws_size;
    const float* X   = (const float*)d_in[0];
    const float* msk = (const float*)d_in[1];
    const float* Wq  = (const float*)d_in[2];  const float* bq = (const float*)d_in[3];
    const float* Wk  = (const float*)d_in[4];  const float* bk = (const float*)d_in[5];
    const float* Wv  = (const float*)d_in[6];  const float* bv = (const float*)d_in[7];
    const float* Wo  = (const float*)d_in[8];  const float* bo = (const float*)d_in[9];
    const float* lg  = (const float*)d_in[10]; const float* lb = (const float*)d_in[11];

    float* out   = (float*)d_out;
    float* probs = out + (size_t)OUT_ELEMS;

    ushort* Qb16  = (ushort*)d_ws;                 // 8388608 bf16 = 16 MB
    ushort* Kb16  = Qb16 + (size_t)8388608;        // 16 MB
    ushort* Vtb16 = Kb16 + (size_t)8388608;        // 16 MB (transposed [bh][d][s])
    float*  CT    = (float*)(Vtb16 + (size_t)8388608);  // 32 MB
    float*  Hb    = CT + (size_t)8388608;               // 32 MB

    gemm_qkv_k<<<dim3(Mrows/BM, HID/BN, 3), 256, 0, stream>>>(X, Wq, Wk, Wv, bq, bk, bv, Qb16, Kb16, Vtb16);
    attn_k<<<dim3(Sz/64, Bz*Hh), 256, 0, stream>>>(Qb16, Kb16, Vtb16, msk, probs, CT);
    gemm_out_k<<<dim3(Mrows/BM, HID/BN), 256, 0, stream>>>(CT, Wo, bo, X, Hb);
    ln_k<<<dim3(Mrows), 256, 0, stream>>>(Hb, lg, lb, out);
}